// Round 9
// baseline (359.235 us; speedup 1.0000x reference)
//
#include <hip/hip_runtime.h>
#include <math.h>

#define EPS 1e-8f
#define MARGIN 0.5f
#define NEG_PER_WAVE 32
#define FIXSCALE 1048576.0f            // 2^20 fixed-point for t
#define MASK40 ((1ULL << 40) - 1)

typedef float    f4 __attribute__((ext_vector_type(4)));
typedef _Float16 h4 __attribute__((ext_vector_type(4)));

__device__ __forceinline__ float dot4(const f4 a, const f4 b) {
    return a.x * b.x + a.y * b.y + a.z * b.z + a.w * b.w;
}
__device__ __forceinline__ float dot4h(const h4 a, const f4 b) {
    return (float)a.x * b.x + (float)a.y * b.y + (float)a.z * b.z + (float)a.w * b.w;
}

// ============================ FP16-anchor path ==============================

// Kernel 1h: pos cosine + normalized fp16 anchor table + zero accums/counter.
__global__ void pos_h_kernel(const float* __restrict__ anchor,
                             const float* __restrict__ pos,
                             _Float16* __restrict__ a_h,
                             float* __restrict__ ps,
                             unsigned long long* __restrict__ acc,
                             unsigned int* __restrict__ done,
                             int B) {
    const int tid  = blockIdx.x * blockDim.x + threadIdx.x;
    const int row  = tid >> 6;
    const int lane = threadIdx.x & 63;

    // zero packed accumulators (2*B u32 words) + done counter
    if (tid < 2 * B) ((unsigned int*)acc)[tid] = 0u;
    if (tid == 0) *done = 0u;

    if (row >= B) return;

    const f4 a = *(reinterpret_cast<const f4*>(anchor + (size_t)row * 256) + lane);
    const f4 p = *(reinterpret_cast<const f4*>(pos    + (size_t)row * 256) + lane);

    float dot = dot4(a, p);
    float na  = dot4(a, a);
    float nb  = dot4(p, p);

    #pragma unroll
    for (int off = 32; off > 0; off >>= 1) {
        dot += __shfl_xor(dot, off);
        na  += __shfl_xor(na,  off);
        nb  += __shfl_xor(nb,  off);
    }
    const float sna   = sqrtf(na);
    const float scale = 1.0f / fmaxf(sna, 1e-20f);

    h4 ah;
    ah.x = (_Float16)(a.x * scale);
    ah.y = (_Float16)(a.y * scale);
    ah.z = (_Float16)(a.z * scale);
    ah.w = (_Float16)(a.w * scale);
    *(reinterpret_cast<h4*>(a_h + (size_t)row * 256) + lane) = ah;

    if (lane == 0)
        ps[row] = dot / fmaxf(sna * sqrtf(nb), EPS);
}

// Kernel 2h: pure-stream hot loop with HOISTED idx (one coalesced load per
// wave, shfl-broadcast per step -> no dependent VMEM load at iteration head).
// One packed u64 atomic per negative at wave end. Finalize fused: last block
// (done-counter) reduces acc -> scalar, saving a dispatch.
__global__ void __launch_bounds__(256) neg_h_kernel(
        const _Float16* __restrict__ a_h,
        const float* __restrict__ neg,
        const int*  __restrict__ idx,
        const float* __restrict__ ps,
        unsigned long long* __restrict__ acc,
        unsigned int* __restrict__ done,
        float* __restrict__ out,
        int N, int B) {
    __shared__ float ssim[4][NEG_PER_WAVE];

    const int lane  = threadIdx.x & 63;
    const int wid   = threadIdx.x >> 6;
    const int group = lane >> 4;
    const int glane = lane & 15;
    const long long base =
        ((long long)blockIdx.x * (blockDim.x >> 6) + wid) * NEG_PER_WAVE;

    // hoisted index load: lanes 0..31 fetch this wave's 32 indices (128 B)
    int b_all = 0;
    {
        const long long in = base + lane;
        if (lane < NEG_PER_WAVE && in < N) b_all = idx[in];
    }

    if (base < N) {
        #pragma unroll 2
        for (int it = 0; it < NEG_PER_WAVE; it += 4) {
            const long long n = base + it + group;
            const bool valid = (n < N);
            const long long ns = valid ? n : (long long)0;
            const int b = __shfl(b_all, it + group);   // register broadcast

            const f4* nr = reinterpret_cast<const f4*>(neg + (size_t)ns * 256);
            const h4* ar = reinterpret_cast<const h4*>(a_h + (size_t)b * 256);

            const f4 v0 = nr[ 0 + glane];
            const f4 v1 = nr[16 + glane];
            const f4 v2 = nr[32 + glane];
            const f4 v3 = nr[48 + glane];
            const h4 a0 = ar[ 0 + glane], a1 = ar[16 + glane],
                     a2 = ar[32 + glane], a3 = ar[48 + glane];

            float d = dot4h(a0, v0) + dot4h(a1, v1) + dot4h(a2, v2) + dot4h(a3, v3);
            float q = dot4(v0, v0) + dot4(v1, v1) + dot4(v2, v2) + dot4(v3, v3);

            #pragma unroll
            for (int off = 8; off > 0; off >>= 1) {
                d += __shfl_xor(d, off);
                q += __shfl_xor(q, off);
            }
            if (glane == 0)
                ssim[wid][it + group] = d * rsqrtf(fmaxf(q, 1e-30f));
        }
    }

    // wave-local flush: lane L owns negative base+L; b is lane's own b_all.
    if (lane < NEG_PER_WAVE && base + lane < N) {
        const float t = fmaxf(MARGIN + ssim[wid][lane] - ps[b_all], 0.0f);
        const unsigned long long pk =
            (unsigned long long)(t * FIXSCALE + 0.5f) + (1ULL << 40);
        atomicAdd(&acc[b_all], pk);
    }

    // ---- fused finalize: last block reduces acc -> scalar ----
    __threadfence();            // each thread drains its own atomics (vmcnt 0)
    __syncthreads();            // whole block done flushing

    __shared__ unsigned int lastflag;
    if (threadIdx.x == 0)
        lastflag = (atomicAdd(done, 1u) == gridDim.x - 1) ? 1u : 0u;
    __syncthreads();

    if (lastflag) {
        float local = 0.0f;
        for (int i = threadIdx.x; i < B; i += blockDim.x) {
            // coherent RMW read: guaranteed to see all blocks' atomics
            const unsigned long long v = atomicAdd(&acc[i], 0ULL);
            const float c = (float)(v >> 40);
            const float s = (float)(v & MASK40) * (1.0f / FIXSCALE);
            local += (c > 0.0f) ? (s / c) : 0.0f;
        }
        #pragma unroll
        for (int off = 32; off > 0; off >>= 1)
            local += __shfl_xor(local, off);

        __shared__ float ws[4];
        if ((threadIdx.x & 63) == 0) ws[threadIdx.x >> 6] = local;
        __syncthreads();
        if (threadIdx.x == 0)
            out[0] = (ws[0] + ws[1] + ws[2] + ws[3]) / (float)B;
    }
}

// ===================== Fallback (R5/R6, known-good, fp32) ===================

__global__ void pos_sim_kernel(const float* __restrict__ anchor,
                               const float* __restrict__ pos,
                               float2* __restrict__ pn,
                               float* __restrict__ sums,
                               float* __restrict__ counts,
                               int B) {
    const int tid  = blockIdx.x * blockDim.x + threadIdx.x;
    const int wave = tid >> 6;
    const int lane = threadIdx.x & 63;
    if (tid < B) sums[tid] = 0.0f;
    else if (tid < 2 * B) counts[tid - B] = 0.0f;
    if (wave >= B) return;
    const f4 a = *(reinterpret_cast<const f4*>(anchor + (size_t)wave * 256) + lane);
    const f4 p = *(reinterpret_cast<const f4*>(pos    + (size_t)wave * 256) + lane);
    float dot = dot4(a, p), na = dot4(a, a), nb = dot4(p, p);
    #pragma unroll
    for (int off = 32; off > 0; off >>= 1) {
        dot += __shfl_xor(dot, off);
        na  += __shfl_xor(na,  off);
        nb  += __shfl_xor(nb,  off);
    }
    if (lane == 0) {
        float sna = sqrtf(na);
        float2 r; r.x = dot / fmaxf(sna * sqrtf(nb), EPS); r.y = sna;
        pn[wave] = r;
    }
}

__global__ void __launch_bounds__(256) neg_kernel(
        const float* __restrict__ anchor,
        const float* __restrict__ neg,
        const int*  __restrict__ idx,
        const float2* __restrict__ pn,
        float* __restrict__ sums,
        float* __restrict__ counts,
        int N) {
    const int lane  = threadIdx.x & 63;
    const int wid   = threadIdx.x >> 6;
    const int group = lane >> 4;
    const int glane = lane & 15;
    const long long base =
        ((long long)blockIdx.x * (blockDim.x >> 6) + wid) * NEG_PER_WAVE;
    if (base >= N) return;
    for (int it = 0; it < NEG_PER_WAVE; it += 4) {
        const long long n = base + it + group;
        if (n >= N) continue;
        const int b = idx[n];
        const f4* ar = reinterpret_cast<const f4*>(anchor + (size_t)b * 256);
        const f4* nr = reinterpret_cast<const f4*>(neg + (size_t)n * 256);
        float d = 0.0f, q = 0.0f;
        #pragma unroll
        for (int c = 0; c < 4; ++c) {
            const f4 a = ar[c * 16 + glane];
            const f4 v = nr[c * 16 + glane];
            d += dot4(a, v); q += dot4(v, v);
        }
        #pragma unroll
        for (int off = 8; off > 0; off >>= 1) {
            d += __shfl_xor(d, off);
            q += __shfl_xor(q, off);
        }
        if (glane == 0) {
            const float2 p = pn[b];
            float t = fmaxf(MARGIN + d / fmaxf(p.y * sqrtf(q), EPS) - p.x, 0.0f);
            atomicAdd(&sums[b], t);
            atomicAdd(&counts[b], 1.0f);
        }
    }
}

__global__ void __launch_bounds__(1024) finalize_kernel(
        const float* __restrict__ sums,
        const float* __restrict__ counts,
        float* __restrict__ out, int B) {
    float local = 0.0f;
    for (int i = threadIdx.x; i < B; i += blockDim.x) {
        float c = counts[i];
        local += (c > 0.0f) ? (sums[i] / c) : 0.0f;
    }
    #pragma unroll
    for (int off = 32; off > 0; off >>= 1)
        local += __shfl_xor(local, off);

    __shared__ float ws[16];
    const int wid = threadIdx.x >> 6;
    if ((threadIdx.x & 63) == 0) ws[wid] = local;
    __syncthreads();
    if (threadIdx.x == 0) {
        float tot = 0.0f;
        const int nw = blockDim.x >> 6;
        for (int w = 0; w < nw; ++w) tot += ws[w];
        out[0] = tot / (float)B;
    }
}

extern "C" void kernel_launch(void* const* d_in, const int* in_sizes, int n_in,
                              void* d_out, int out_size, void* d_ws, size_t ws_size,
                              hipStream_t stream) {
    const float* anchor = (const float*)d_in[0];
    const float* pos    = (const float*)d_in[1];
    const float* neg    = (const float*)d_in[2];
    const int*   idx    = (const int*)d_in[3];

    const int D = 256;
    int B = in_sizes[0] / D;   // 4096
    int N = in_sizes[3];       // 262144

    const size_t need_h = (size_t)B * 256 * sizeof(_Float16)            // a_h
                        + (size_t)B * sizeof(float)                     // ps
                        + (size_t)B * sizeof(unsigned long long)        // acc
                        + 64;                                           // done

    const int threads = 256;
    const int negs_per_block = (threads / 64) * NEG_PER_WAVE;           // 128
    const int nblocks = (N + negs_per_block - 1) / negs_per_block;      // 2048

    if (ws_size >= need_h) {
        _Float16*           a_h  = (_Float16*)d_ws;
        float*              ps   = (float*)(a_h + (size_t)B * 256);
        unsigned long long* acc  = (unsigned long long*)(ps + B);
        unsigned int*       done = (unsigned int*)(acc + B);

        pos_h_kernel<<<(B + 3) / 4, threads, 0, stream>>>(anchor, pos, a_h, ps,
                                                          acc, done, B);
        neg_h_kernel<<<nblocks, threads, 0, stream>>>(a_h, neg, idx, ps, acc,
                                                      done, (float*)d_out, N, B);
    } else {
        // fallback: known-good fp32 path
        float2* pn     = (float2*)d_ws;
        float*  sums   = (float*)(pn + B);
        float*  counts = sums + B;

        pos_sim_kernel<<<(B + 3) / 4, threads, 0, stream>>>(anchor, pos, pn,
                                                            sums, counts, B);
        neg_kernel<<<nblocks, threads, 0, stream>>>(anchor, neg, idx, pn,
                                                    sums, counts, N);
        finalize_kernel<<<1, 1024, 0, stream>>>(sums, counts, (float*)d_out, B);
    }
}

// Round 10
// 61.791 us; speedup vs baseline: 5.8137x; 5.8137x over previous
//
#include <hip/hip_runtime.h>
#include <math.h>

#define EPS 1e-8f
#define MARGIN 0.5f
#define NEG_PER_WAVE 32
#define FIXSCALE 1048576.0f            // 2^20 fixed-point for t
#define MASK40 ((1ULL << 40) - 1)

typedef float    f4 __attribute__((ext_vector_type(4)));
typedef _Float16 h4 __attribute__((ext_vector_type(4)));

__device__ __forceinline__ float dot4(const f4 a, const f4 b) {
    return a.x * b.x + a.y * b.y + a.z * b.z + a.w * b.w;
}
__device__ __forceinline__ float dot4h(const h4 a, const f4 b) {
    return (float)a.x * b.x + (float)a.y * b.y + (float)a.z * b.z + (float)a.w * b.w;
}

// ============================ FP16-anchor path ==============================

// Kernel 1h: pos cosine + normalized fp16 anchor table + zero u64 accums.
__global__ void pos_h_kernel(const float* __restrict__ anchor,
                             const float* __restrict__ pos,
                             _Float16* __restrict__ a_h,
                             float* __restrict__ ps,
                             unsigned long long* __restrict__ acc,
                             int B) {
    const int tid  = blockIdx.x * blockDim.x + threadIdx.x;
    const int row  = tid >> 6;
    const int lane = threadIdx.x & 63;

    // zero packed accumulators (2*B u32 words; total threads = 64*B >= 2*B)
    if (tid < 2 * B) ((unsigned int*)acc)[tid] = 0u;

    if (row >= B) return;

    const f4 a = *(reinterpret_cast<const f4*>(anchor + (size_t)row * 256) + lane);
    const f4 p = *(reinterpret_cast<const f4*>(pos    + (size_t)row * 256) + lane);

    float dot = dot4(a, p);
    float na  = dot4(a, a);
    float nb  = dot4(p, p);

    #pragma unroll
    for (int off = 32; off > 0; off >>= 1) {
        dot += __shfl_xor(dot, off);
        na  += __shfl_xor(na,  off);
        nb  += __shfl_xor(nb,  off);
    }
    const float sna   = sqrtf(na);
    const float scale = 1.0f / fmaxf(sna, 1e-20f);

    h4 ah;
    ah.x = (_Float16)(a.x * scale);
    ah.y = (_Float16)(a.y * scale);
    ah.z = (_Float16)(a.z * scale);
    ah.w = (_Float16)(a.w * scale);
    *(reinterpret_cast<h4*>(a_h + (size_t)row * 256) + lane) = ah;

    if (lane == 0)
        ps[row] = dot / fmaxf(sna * sqrtf(nb), EPS);
}

// Kernel 2h: pure-stream hot loop; idx hoisted into registers (one coalesced
// 128 B load per wave, shfl-broadcast per step). unroll-4 -> up to 32 loads
// in flight per wave. One packed u64 atomic per negative at wave end.
// NO threadfence, NO fused finalize (device-scope fences thrash per-XCD L2).
__global__ void __launch_bounds__(256) neg_h_kernel(
        const _Float16* __restrict__ a_h,
        const float* __restrict__ neg,
        const int*  __restrict__ idx,
        const float* __restrict__ ps,
        unsigned long long* __restrict__ acc,
        int N) {
    __shared__ float ssim[4][NEG_PER_WAVE];

    const int lane  = threadIdx.x & 63;
    const int wid   = threadIdx.x >> 6;
    const int group = lane >> 4;
    const int glane = lane & 15;
    const long long base =
        ((long long)blockIdx.x * (blockDim.x >> 6) + wid) * NEG_PER_WAVE;

    // hoisted index load: lanes 0..31 fetch this wave's 32 indices (128 B)
    int b_all = 0;
    {
        const long long in = base + lane;
        if (lane < NEG_PER_WAVE && in < N) b_all = idx[in];
    }

    if (base < N) {
        #pragma unroll 4
        for (int it = 0; it < NEG_PER_WAVE; it += 4) {
            const long long n = base + it + group;
            const bool valid = (n < N);
            const long long ns = valid ? n : (long long)0;
            const int b = __shfl(b_all, it + group);   // register broadcast

            const f4* nr = reinterpret_cast<const f4*>(neg + (size_t)ns * 256);
            const h4* ar = reinterpret_cast<const h4*>(a_h + (size_t)b * 256);

            const f4 v0 = nr[ 0 + glane];
            const f4 v1 = nr[16 + glane];
            const f4 v2 = nr[32 + glane];
            const f4 v3 = nr[48 + glane];
            const h4 a0 = ar[ 0 + glane], a1 = ar[16 + glane],
                     a2 = ar[32 + glane], a3 = ar[48 + glane];

            float d = dot4h(a0, v0) + dot4h(a1, v1) + dot4h(a2, v2) + dot4h(a3, v3);
            float q = dot4(v0, v0) + dot4(v1, v1) + dot4(v2, v2) + dot4(v3, v3);

            #pragma unroll
            for (int off = 8; off > 0; off >>= 1) {
                d += __shfl_xor(d, off);
                q += __shfl_xor(q, off);
            }
            if (glane == 0)
                ssim[wid][it + group] = d * rsqrtf(fmaxf(q, 1e-30f));
        }
    }

    // wave-local flush: lane L owns negative base+L; b is lane's own b_all.
    if (lane < NEG_PER_WAVE && base + lane < N) {
        const float t = fmaxf(MARGIN + ssim[wid][lane] - ps[b_all], 0.0f);
        const unsigned long long pk =
            (unsigned long long)(t * FIXSCALE + 0.5f) + (1ULL << 40);
        atomicAdd(&acc[b_all], pk);
    }
}

// Kernel 3h: unpack u64 accums -> segment means -> scalar (one block).
__global__ void __launch_bounds__(1024) finalize_packed_kernel(
        const unsigned long long* __restrict__ acc,
        float* __restrict__ out, int B) {
    float local = 0.0f;
    for (int i = threadIdx.x; i < B; i += blockDim.x) {
        const unsigned long long v = acc[i];
        const float c = (float)(v >> 40);
        const float s = (float)(v & MASK40) * (1.0f / FIXSCALE);
        local += (c > 0.0f) ? (s / c) : 0.0f;
    }
    #pragma unroll
    for (int off = 32; off > 0; off >>= 1)
        local += __shfl_xor(local, off);

    __shared__ float ws[16];
    const int wid = threadIdx.x >> 6;
    if ((threadIdx.x & 63) == 0) ws[wid] = local;
    __syncthreads();
    if (threadIdx.x == 0) {
        float tot = 0.0f;
        const int nw = blockDim.x >> 6;
        for (int w = 0; w < nw; ++w) tot += ws[w];
        out[0] = tot / (float)B;
    }
}

// ===================== Fallback (R5/R6, known-good, fp32) ===================

__global__ void pos_sim_kernel(const float* __restrict__ anchor,
                               const float* __restrict__ pos,
                               float2* __restrict__ pn,
                               float* __restrict__ sums,
                               float* __restrict__ counts,
                               int B) {
    const int tid  = blockIdx.x * blockDim.x + threadIdx.x;
    const int wave = tid >> 6;
    const int lane = threadIdx.x & 63;
    if (tid < B) sums[tid] = 0.0f;
    else if (tid < 2 * B) counts[tid - B] = 0.0f;
    if (wave >= B) return;
    const f4 a = *(reinterpret_cast<const f4*>(anchor + (size_t)wave * 256) + lane);
    const f4 p = *(reinterpret_cast<const f4*>(pos    + (size_t)wave * 256) + lane);
    float dot = dot4(a, p), na = dot4(a, a), nb = dot4(p, p);
    #pragma unroll
    for (int off = 32; off > 0; off >>= 1) {
        dot += __shfl_xor(dot, off);
        na  += __shfl_xor(na,  off);
        nb  += __shfl_xor(nb,  off);
    }
    if (lane == 0) {
        float sna = sqrtf(na);
        float2 r; r.x = dot / fmaxf(sna * sqrtf(nb), EPS); r.y = sna;
        pn[wave] = r;
    }
}

__global__ void __launch_bounds__(256) neg_kernel(
        const float* __restrict__ anchor,
        const float* __restrict__ neg,
        const int*  __restrict__ idx,
        const float2* __restrict__ pn,
        float* __restrict__ sums,
        float* __restrict__ counts,
        int N) {
    const int lane  = threadIdx.x & 63;
    const int wid   = threadIdx.x >> 6;
    const int group = lane >> 4;
    const int glane = lane & 15;
    const long long base =
        ((long long)blockIdx.x * (blockDim.x >> 6) + wid) * NEG_PER_WAVE;
    if (base >= N) return;
    for (int it = 0; it < NEG_PER_WAVE; it += 4) {
        const long long n = base + it + group;
        if (n >= N) continue;
        const int b = idx[n];
        const f4* ar = reinterpret_cast<const f4*>(anchor + (size_t)b * 256);
        const f4* nr = reinterpret_cast<const f4*>(neg + (size_t)n * 256);
        float d = 0.0f, q = 0.0f;
        #pragma unroll
        for (int c = 0; c < 4; ++c) {
            const f4 a = ar[c * 16 + glane];
            const f4 v = nr[c * 16 + glane];
            d += dot4(a, v); q += dot4(v, v);
        }
        #pragma unroll
        for (int off = 8; off > 0; off >>= 1) {
            d += __shfl_xor(d, off);
            q += __shfl_xor(q, off);
        }
        if (glane == 0) {
            const float2 p = pn[b];
            float t = fmaxf(MARGIN + d / fmaxf(p.y * sqrtf(q), EPS) - p.x, 0.0f);
            atomicAdd(&sums[b], t);
            atomicAdd(&counts[b], 1.0f);
        }
    }
}

__global__ void __launch_bounds__(1024) finalize_kernel(
        const float* __restrict__ sums,
        const float* __restrict__ counts,
        float* __restrict__ out, int B) {
    float local = 0.0f;
    for (int i = threadIdx.x; i < B; i += blockDim.x) {
        float c = counts[i];
        local += (c > 0.0f) ? (sums[i] / c) : 0.0f;
    }
    #pragma unroll
    for (int off = 32; off > 0; off >>= 1)
        local += __shfl_xor(local, off);

    __shared__ float ws[16];
    const int wid = threadIdx.x >> 6;
    if ((threadIdx.x & 63) == 0) ws[wid] = local;
    __syncthreads();
    if (threadIdx.x == 0) {
        float tot = 0.0f;
        const int nw = blockDim.x >> 6;
        for (int w = 0; w < nw; ++w) tot += ws[w];
        out[0] = tot / (float)B;
    }
}

extern "C" void kernel_launch(void* const* d_in, const int* in_sizes, int n_in,
                              void* d_out, int out_size, void* d_ws, size_t ws_size,
                              hipStream_t stream) {
    const float* anchor = (const float*)d_in[0];
    const float* pos    = (const float*)d_in[1];
    const float* neg    = (const float*)d_in[2];
    const int*   idx    = (const int*)d_in[3];

    const int D = 256;
    int B = in_sizes[0] / D;   // 4096
    int N = in_sizes[3];       // 262144

    const size_t need_h = (size_t)B * 256 * sizeof(_Float16)            // a_h
                        + (size_t)B * sizeof(float)                     // ps
                        + (size_t)B * sizeof(unsigned long long);       // acc

    const int threads = 256;
    const int negs_per_block = (threads / 64) * NEG_PER_WAVE;           // 128
    const int nblocks = (N + negs_per_block - 1) / negs_per_block;      // 2048

    if (ws_size >= need_h) {
        _Float16*           a_h = (_Float16*)d_ws;
        float*              ps  = (float*)(a_h + (size_t)B * 256);
        unsigned long long* acc = (unsigned long long*)(ps + B);

        pos_h_kernel<<<(B + 3) / 4, threads, 0, stream>>>(anchor, pos, a_h, ps,
                                                          acc, B);
        neg_h_kernel<<<nblocks, threads, 0, stream>>>(a_h, neg, idx, ps,
                                                      acc, N);
        finalize_packed_kernel<<<1, 1024, 0, stream>>>(acc, (float*)d_out, B);
    } else {
        // fallback: known-good fp32 path
        float2* pn     = (float2*)d_ws;
        float*  sums   = (float*)(pn + B);
        float*  counts = sums + B;

        pos_sim_kernel<<<(B + 3) / 4, threads, 0, stream>>>(anchor, pos, pn,
                                                            sums, counts, B);
        neg_kernel<<<nblocks, threads, 0, stream>>>(anchor, neg, idx, pn,
                                                    sums, counts, N);
        finalize_kernel<<<1, 1024, 0, stream>>>(sums, counts, (float*)d_out, B);
    }
}

// Round 11
// 61.684 us; speedup vs baseline: 5.8238x; 1.0017x over previous
//
#include <hip/hip_runtime.h>
#include <math.h>

#define EPS 1e-8f
#define MARGIN 0.5f
#define NEG_PER_WAVE 32
#define FIXSCALE 1048576.0f            // 2^20 fixed-point for t
#define MASK40 ((1ULL << 40) - 1)

typedef float    f4 __attribute__((ext_vector_type(4)));
typedef _Float16 h4 __attribute__((ext_vector_type(4)));

__device__ __forceinline__ float dot4(const f4 a, const f4 b) {
    return a.x * b.x + a.y * b.y + a.z * b.z + a.w * b.w;
}
__device__ __forceinline__ float dot4h(const h4 a, const f4 b) {
    return (float)a.x * b.x + (float)a.y * b.y + (float)a.z * b.z + (float)a.w * b.w;
}

// ============================ FP16-anchor path ==============================

// Kernel 1h: pos cosine + normalized fp16 anchor table + zero u64 accums.
__global__ void pos_h_kernel(const float* __restrict__ anchor,
                             const float* __restrict__ pos,
                             _Float16* __restrict__ a_h,
                             float* __restrict__ ps,
                             unsigned long long* __restrict__ acc,
                             int B) {
    const int tid  = blockIdx.x * blockDim.x + threadIdx.x;
    const int row  = tid >> 6;
    const int lane = threadIdx.x & 63;

    if (tid < 2 * B) ((unsigned int*)acc)[tid] = 0u;

    if (row >= B) return;

    const f4 a = *(reinterpret_cast<const f4*>(anchor + (size_t)row * 256) + lane);
    const f4 p = *(reinterpret_cast<const f4*>(pos    + (size_t)row * 256) + lane);

    float dot = dot4(a, p);
    float na  = dot4(a, a);
    float nb  = dot4(p, p);

    #pragma unroll
    for (int off = 32; off > 0; off >>= 1) {
        dot += __shfl_xor(dot, off);
        na  += __shfl_xor(na,  off);
        nb  += __shfl_xor(nb,  off);
    }
    const float sna   = sqrtf(na);
    const float scale = 1.0f / fmaxf(sna, 1e-20f);

    h4 ah;
    ah.x = (_Float16)(a.x * scale);
    ah.y = (_Float16)(a.y * scale);
    ah.z = (_Float16)(a.z * scale);
    ah.w = (_Float16)(a.w * scale);
    *(reinterpret_cast<h4*>(a_h + (size_t)row * 256) + lane) = ah;

    if (lane == 0)
        ps[row] = dot / fmaxf(sna * sqrtf(nb), EPS);
}

// Kernel 2h: explicit 2-deep software pipeline. Two named register sets
// (A/B); one step's 8 loads always outstanding while computing the previous
// step (static names, fully unrolled 8 steps -> counted-vmcnt at source
// level). idx hoisted; one packed u64 atomic per negative at wave end.
__global__ void __launch_bounds__(256) neg_h_kernel(
        const _Float16* __restrict__ a_h,
        const float* __restrict__ neg,
        const int*  __restrict__ idx,
        const float* __restrict__ ps,
        unsigned long long* __restrict__ acc,
        int N) {
    __shared__ float ssim[4][NEG_PER_WAVE];

    const int lane  = threadIdx.x & 63;
    const int wid   = threadIdx.x >> 6;
    const int group = lane >> 4;
    const int glane = lane & 15;
    const long long base =
        ((long long)blockIdx.x * (blockDim.x >> 6) + wid) * NEG_PER_WAVE;

    // hoisted index load: lanes 0..31 fetch this wave's 32 indices (128 B)
    int b_all = 0;
    {
        const long long in = base + lane;
        if (lane < NEG_PER_WAVE && in < N) b_all = idx[in];
    }

    if (base + NEG_PER_WAVE <= N) {
        // ---------------- fast path: full tile, 2-deep pipeline ------------
        f4 v0A, v1A, v2A, v3A, v0B, v1B, v2B, v3B;
        h4 a0A, a1A, a2A, a3A, a0B, a1B, a2B, a3B;

#define LOADS(S, IT) do {                                                     \
        const long long n_ = base + (IT) + group;                            \
        const f4* nr_ = reinterpret_cast<const f4*>(neg + (size_t)n_ * 256); \
        v0##S = nr_[ 0 + glane];                                             \
        v1##S = nr_[16 + glane];                                             \
        v2##S = nr_[32 + glane];                                             \
        v3##S = nr_[48 + glane];                                             \
        const int b_ = __shfl(b_all, (IT) + group);                          \
        const h4* ar_ = reinterpret_cast<const h4*>(a_h + (size_t)b_ * 256); \
        a0##S = ar_[ 0 + glane];                                             \
        a1##S = ar_[16 + glane];                                             \
        a2##S = ar_[32 + glane];                                             \
        a3##S = ar_[48 + glane];                                             \
    } while (0)

#define COMPS(S, IT) do {                                                     \
        float d_ = dot4h(a0##S, v0##S) + dot4h(a1##S, v1##S)                 \
                 + dot4h(a2##S, v2##S) + dot4h(a3##S, v3##S);                \
        float q_ = dot4(v0##S, v0##S) + dot4(v1##S, v1##S)                   \
                 + dot4(v2##S, v2##S) + dot4(v3##S, v3##S);                  \
        _Pragma("unroll")                                                     \
        for (int off_ = 8; off_ > 0; off_ >>= 1) {                           \
            d_ += __shfl_xor(d_, off_);                                      \
            q_ += __shfl_xor(q_, off_);                                      \
        }                                                                     \
        if (glane == 0)                                                       \
            ssim[wid][(IT) + group] = d_ * rsqrtf(fmaxf(q_, 1e-30f));        \
    } while (0)

        LOADS(A, 0);  LOADS(B, 4);
        COMPS(A, 0);  LOADS(A, 8);
        COMPS(B, 4);  LOADS(B, 12);
        COMPS(A, 8);  LOADS(A, 16);
        COMPS(B, 12); LOADS(B, 20);
        COMPS(A, 16); LOADS(A, 24);
        COMPS(B, 20); LOADS(B, 28);
        COMPS(A, 24);
        COMPS(B, 28);

#undef LOADS
#undef COMPS
    } else if (base < N) {
        // ---------------- slow path: partial tile (guarded) ----------------
        for (int it = 0; it < NEG_PER_WAVE; it += 4) {
            const long long n = base + it + group;
            const bool valid = (n < N);
            const long long ns = valid ? n : (long long)0;
            const int b = __shfl(b_all, it + group);

            const f4* nr = reinterpret_cast<const f4*>(neg + (size_t)ns * 256);
            const h4* ar = reinterpret_cast<const h4*>(a_h + (size_t)b * 256);

            const f4 v0 = nr[ 0 + glane];
            const f4 v1 = nr[16 + glane];
            const f4 v2 = nr[32 + glane];
            const f4 v3 = nr[48 + glane];
            const h4 a0 = ar[ 0 + glane], a1 = ar[16 + glane],
                     a2 = ar[32 + glane], a3 = ar[48 + glane];

            float d = dot4h(a0, v0) + dot4h(a1, v1) + dot4h(a2, v2) + dot4h(a3, v3);
            float q = dot4(v0, v0) + dot4(v1, v1) + dot4(v2, v2) + dot4(v3, v3);

            #pragma unroll
            for (int off = 8; off > 0; off >>= 1) {
                d += __shfl_xor(d, off);
                q += __shfl_xor(q, off);
            }
            if (glane == 0 && valid)
                ssim[wid][it + group] = d * rsqrtf(fmaxf(q, 1e-30f));
        }
    }

    // wave-local flush: lane L owns negative base+L; b is lane's own b_all.
    if (lane < NEG_PER_WAVE && base + lane < N) {
        const float t = fmaxf(MARGIN + ssim[wid][lane] - ps[b_all], 0.0f);
        const unsigned long long pk =
            (unsigned long long)(t * FIXSCALE + 0.5f) + (1ULL << 40);
        atomicAdd(&acc[b_all], pk);
    }
}

// Kernel 3h: unpack u64 accums -> segment means -> scalar (one block).
__global__ void __launch_bounds__(1024) finalize_packed_kernel(
        const unsigned long long* __restrict__ acc,
        float* __restrict__ out, int B) {
    float local = 0.0f;
    for (int i = threadIdx.x; i < B; i += blockDim.x) {
        const unsigned long long v = acc[i];
        const float c = (float)(v >> 40);
        const float s = (float)(v & MASK40) * (1.0f / FIXSCALE);
        local += (c > 0.0f) ? (s / c) : 0.0f;
    }
    #pragma unroll
    for (int off = 32; off > 0; off >>= 1)
        local += __shfl_xor(local, off);

    __shared__ float ws[16];
    const int wid = threadIdx.x >> 6;
    if ((threadIdx.x & 63) == 0) ws[wid] = local;
    __syncthreads();
    if (threadIdx.x == 0) {
        float tot = 0.0f;
        const int nw = blockDim.x >> 6;
        for (int w = 0; w < nw; ++w) tot += ws[w];
        out[0] = tot / (float)B;
    }
}

// ===================== Fallback (R5/R6, known-good, fp32) ===================

__global__ void pos_sim_kernel(const float* __restrict__ anchor,
                               const float* __restrict__ pos,
                               float2* __restrict__ pn,
                               float* __restrict__ sums,
                               float* __restrict__ counts,
                               int B) {
    const int tid  = blockIdx.x * blockDim.x + threadIdx.x;
    const int wave = tid >> 6;
    const int lane = threadIdx.x & 63;
    if (tid < B) sums[tid] = 0.0f;
    else if (tid < 2 * B) counts[tid - B] = 0.0f;
    if (wave >= B) return;
    const f4 a = *(reinterpret_cast<const f4*>(anchor + (size_t)wave * 256) + lane);
    const f4 p = *(reinterpret_cast<const f4*>(pos    + (size_t)wave * 256) + lane);
    float dot = dot4(a, p), na = dot4(a, a), nb = dot4(p, p);
    #pragma unroll
    for (int off = 32; off > 0; off >>= 1) {
        dot += __shfl_xor(dot, off);
        na  += __shfl_xor(na,  off);
        nb  += __shfl_xor(nb,  off);
    }
    if (lane == 0) {
        float sna = sqrtf(na);
        float2 r; r.x = dot / fmaxf(sna * sqrtf(nb), EPS); r.y = sna;
        pn[wave] = r;
    }
}

__global__ void __launch_bounds__(256) neg_kernel(
        const float* __restrict__ anchor,
        const float* __restrict__ neg,
        const int*  __restrict__ idx,
        const float2* __restrict__ pn,
        float* __restrict__ sums,
        float* __restrict__ counts,
        int N) {
    const int lane  = threadIdx.x & 63;
    const int wid   = threadIdx.x >> 6;
    const int group = lane >> 4;
    const int glane = lane & 15;
    const long long base =
        ((long long)blockIdx.x * (blockDim.x >> 6) + wid) * NEG_PER_WAVE;
    if (base >= N) return;
    for (int it = 0; it < NEG_PER_WAVE; it += 4) {
        const long long n = base + it + group;
        if (n >= N) continue;
        const int b = idx[n];
        const f4* ar = reinterpret_cast<const f4*>(anchor + (size_t)b * 256);
        const f4* nr = reinterpret_cast<const f4*>(neg + (size_t)n * 256);
        float d = 0.0f, q = 0.0f;
        #pragma unroll
        for (int c = 0; c < 4; ++c) {
            const f4 a = ar[c * 16 + glane];
            const f4 v = nr[c * 16 + glane];
            d += dot4(a, v); q += dot4(v, v);
        }
        #pragma unroll
        for (int off = 8; off > 0; off >>= 1) {
            d += __shfl_xor(d, off);
            q += __shfl_xor(q, off);
        }
        if (glane == 0) {
            const float2 p = pn[b];
            float t = fmaxf(MARGIN + d / fmaxf(p.y * sqrtf(q), EPS) - p.x, 0.0f);
            atomicAdd(&sums[b], t);
            atomicAdd(&counts[b], 1.0f);
        }
    }
}

__global__ void __launch_bounds__(1024) finalize_kernel(
        const float* __restrict__ sums,
        const float* __restrict__ counts,
        float* __restrict__ out, int B) {
    float local = 0.0f;
    for (int i = threadIdx.x; i < B; i += blockDim.x) {
        float c = counts[i];
        local += (c > 0.0f) ? (sums[i] / c) : 0.0f;
    }
    #pragma unroll
    for (int off = 32; off > 0; off >>= 1)
        local += __shfl_xor(local, off);

    __shared__ float ws[16];
    const int wid = threadIdx.x >> 6;
    if ((threadIdx.x & 63) == 0) ws[wid] = local;
    __syncthreads();
    if (threadIdx.x == 0) {
        float tot = 0.0f;
        const int nw = blockDim.x >> 6;
        for (int w = 0; w < nw; ++w) tot += ws[w];
        out[0] = tot / (float)B;
    }
}

extern "C" void kernel_launch(void* const* d_in, const int* in_sizes, int n_in,
                              void* d_out, int out_size, void* d_ws, size_t ws_size,
                              hipStream_t stream) {
    const float* anchor = (const float*)d_in[0];
    const float* pos    = (const float*)d_in[1];
    const float* neg    = (const float*)d_in[2];
    const int*   idx    = (const int*)d_in[3];

    const int D = 256;
    int B = in_sizes[0] / D;   // 4096
    int N = in_sizes[3];       // 262144

    const size_t need_h = (size_t)B * 256 * sizeof(_Float16)            // a_h
                        + (size_t)B * sizeof(float)                     // ps
                        + (size_t)B * sizeof(unsigned long long);       // acc

    const int threads = 256;
    const int negs_per_block = (threads / 64) * NEG_PER_WAVE;           // 128
    const int nblocks = (N + negs_per_block - 1) / negs_per_block;      // 2048

    if (ws_size >= need_h) {
        _Float16*           a_h = (_Float16*)d_ws;
        float*              ps  = (float*)(a_h + (size_t)B * 256);
        unsigned long long* acc = (unsigned long long*)(ps + B);

        pos_h_kernel<<<(B + 3) / 4, threads, 0, stream>>>(anchor, pos, a_h, ps,
                                                          acc, B);
        neg_h_kernel<<<nblocks, threads, 0, stream>>>(a_h, neg, idx, ps,
                                                      acc, N);
        finalize_packed_kernel<<<1, 1024, 0, stream>>>(acc, (float*)d_out, B);
    } else {
        // fallback: known-good fp32 path
        float2* pn     = (float2*)d_ws;
        float*  sums   = (float*)(pn + B);
        float*  counts = sums + B;

        pos_sim_kernel<<<(B + 3) / 4, threads, 0, stream>>>(anchor, pos, pn,
                                                            sums, counts, B);
        neg_kernel<<<nblocks, threads, 0, stream>>>(anchor, neg, idx, pn,
                                                    sums, counts, N);
        finalize_kernel<<<1, 1024, 0, stream>>>(sums, counts, (float*)d_out, B);
    }
}